// Round 1
// baseline (169.043 us; speedup 1.0000x reference)
//
#include <hip/hip_runtime.h>
#include <stdint.h>

#define NTOT 8192
#define NX   4096
#define DIM  256

typedef unsigned short u16;
typedef __attribute__((ext_vector_type(8))) short  bf16x8;
typedef __attribute__((ext_vector_type(4))) float  f32x4;

// ---- workspace layout (bytes) ----
// totbf : u16 [8192*256]          = 4,194,304
// sq    : float[8192]             =    32,768
// colp  : float[32*256]           =    32,768
// c2    : float[4]                =        16
// part  : double[4096]            =    32,768
// total ~ 4.3 MB
#define OFF_TOTBF   0
#define OFF_SQ      (4194304)
#define OFF_COLP    (OFF_SQ + 32768)
#define OFF_C2      (OFF_COLP + 32768)
#define OFF_PART    (OFF_C2 + 16)

__device__ __forceinline__ u16 f2bf(float f) {
  union { float f; unsigned int u; } v; v.f = f;
  unsigned int u = v.u;
  u += 0x7fffu + ((u >> 16) & 1u);           // round-to-nearest-even
  return (u16)(u >> 16);
}

__device__ __forceinline__ void gload16(const u16* g, u16* l) {
  // async global->LDS, 16B per lane; LDS dest = wave-uniform base + lane*16
  __builtin_amdgcn_global_load_lds(
      (const __attribute__((address_space(1))) unsigned int*)g,
      (__attribute__((address_space(3))) unsigned int*)l,
      16, 0, 0);
}

// ---- K1: per-row ||t_i||^2 + fp32->bf16 conversion. 2048 blocks x 256 ----
__global__ __launch_bounds__(256) void k_rows(const float* __restrict__ x,
                                              const float* __restrict__ y,
                                              u16* __restrict__ totbf,
                                              float* __restrict__ sq) {
  const int wave = threadIdx.x >> 6, lane = threadIdx.x & 63;
  const int r = blockIdx.x * 4 + wave;
  const float* row = (r < NX) ? (x + (size_t)r * DIM) : (y + (size_t)(r - NX) * DIM);
  float4 v = ((const float4*)row)[lane];
  ushort4 o;
  o.x = f2bf(v.x); o.y = f2bf(v.y); o.z = f2bf(v.z); o.w = f2bf(v.w);
  ((ushort4*)(totbf + (size_t)r * DIM))[lane] = o;
  float s = v.x * v.x + v.y * v.y + v.z * v.z + v.w * v.w;
  #pragma unroll
  for (int off = 32; off; off >>= 1) s += __shfl_down(s, off, 64);
  if (lane == 0) sq[r] = s;
}

// ---- K2: column-sum partials. 32 blocks x 256 (thread = column) ----
__global__ __launch_bounds__(256) void k_cols(const float* __restrict__ x,
                                              const float* __restrict__ y,
                                              float* __restrict__ colp) {
  const int c = threadIdx.x, b = blockIdx.x;
  float s = 0.0f;
  for (int r0 = 0; r0 < 256; ++r0) {
    int r = b * 256 + r0;
    const float* row = (r < NX) ? (x + (size_t)r * DIM) : (y + (size_t)(r - NX) * DIM);
    s += row[c];
  }
  colp[b * 256 + c] = s;
}

// ---- K3: bandwidth -> c2 = 1/(16*bw*ln2). 1 block x 256 ----
__global__ __launch_bounds__(256) void k_scalar(const float* __restrict__ sq,
                                                const float* __restrict__ colp,
                                                float* __restrict__ c2out) {
  __shared__ double red[256];
  const int t = threadIdx.x;
  double s1 = 0.0;
  for (int i = t; i < NTOT; i += 256) s1 += (double)sq[i];
  red[t] = s1; __syncthreads();
  for (int off = 128; off; off >>= 1) { if (t < off) red[t] += red[t + off]; __syncthreads(); }
  double S1 = red[0]; __syncthreads();
  double cs = 0.0;
  for (int b = 0; b < 32; ++b) cs += (double)colp[b * 256 + t];
  red[t] = cs * cs; __syncthreads();
  for (int off = 128; off; off >>= 1) { if (t < off) red[t] += red[t + off]; __syncthreads(); }
  if (t == 0) {
    double CS2 = red[0];
    double n = (double)NTOT;
    double S = 2.0 * n * S1 - 2.0 * CS2;          // sum(L2), clipping negligible
    double bw = S / (n * n - n);
    bw *= 0.25;                                    // / KERNEL_MUL^(KERNEL_NUM//2)
    c2out[0] = (float)(1.0 / (16.0 * bw * 0.6931471805599453)); // exp(-L2/(16bw)) = 2^(-L2*c2)
  }
}

// ---- K4: fused gram + 5-kernel RBF + signed tile sum. 64x64 blocks x 256 ----
__global__ __launch_bounds__(256) void k_main(const u16* __restrict__ totbf,
                                              const float* __restrict__ sq,
                                              const float* __restrict__ c2p,
                                              double* __restrict__ part) {
  __shared__ u16 sA[128 * 32];
  __shared__ u16 sB[128 * 32];
  const int tid  = threadIdx.x;
  const int wave = tid >> 6, lane = tid & 63;
  const int quad = lane >> 4, l16 = lane & 15;
  const int bj = blockIdx.x, bi = blockIdx.y;
  const int wm = wave >> 1, wn = wave & 1;

  f32x4 acc[4][4];
  #pragma unroll
  for (int tm = 0; tm < 4; ++tm)
    #pragma unroll
    for (int tn = 0; tn < 4; ++tn) {
      acc[tm][tn][0] = 0.0f; acc[tm][tn][1] = 0.0f;
      acc[tm][tn][2] = 0.0f; acc[tm][tn][3] = 0.0f;
    }

  const int crow = lane >> 2;          // row within 16-row chunk
  const int ccol = (lane & 3) * 8;     // element offset within 32-wide k-slice

  for (int kk = 0; kk < DIM; kk += 32) {
    if (kk) __syncthreads();           // protect LDS from overwrite
    #pragma unroll
    for (int c = 0; c < 4; ++c) {
      const int chunk = wave * 4 + c;  // 0..15: 0-7 = A, 8-15 = B
      const int isB = chunk >> 3;
      const int ch  = chunk & 7;
      const int growl = (isB ? bj : bi) * 128 + ch * 16 + crow;
      const u16* g = totbf + (size_t)growl * DIM + kk + ccol;
      gload16(g, (isB ? sB : sA) + ch * 512);
    }
    __syncthreads();                   // compiler emits vmcnt(0) before barrier

    bf16x8 af[4], bfr[4];
    #pragma unroll
    for (int tm = 0; tm < 4; ++tm)
      af[tm] = *(const bf16x8*)&sA[(wm * 64 + tm * 16 + l16) * 32 + quad * 8];
    #pragma unroll
    for (int tn = 0; tn < 4; ++tn)
      bfr[tn] = *(const bf16x8*)&sB[(wn * 64 + tn * 16 + l16) * 32 + quad * 8];
    #pragma unroll
    for (int tm = 0; tm < 4; ++tm)
      #pragma unroll
      for (int tn = 0; tn < 4; ++tn)
        acc[tm][tn] = __builtin_amdgcn_mfma_f32_16x16x32_bf16(af[tm], bfr[tn], acc[tm][tn], 0, 0, 0);
  }

  // ---- epilogue: L2 -> u + u^2 + u^4 + u^8 + u^16, signed ----
  const float c2 = c2p[0];
  const int gi0 = bi * 128 + wm * 64;
  const int gj0 = bj * 128 + wn * 64;
  float lsum = 0.0f;
  #pragma unroll
  for (int tn = 0; tn < 4; ++tn) {
    const float sqj = sq[gj0 + tn * 16 + l16];
    #pragma unroll
    for (int tm = 0; tm < 4; ++tm) {
      const f32x4 sqi = *(const f32x4*)&sq[gi0 + tm * 16 + quad * 4];
      const f32x4 a = acc[tm][tn];
      #pragma unroll
      for (int r = 0; r < 4; ++r) {
        float d2 = sqi[r] + sqj - 2.0f * a[r];
        d2 = fmaxf(d2, 0.0f);
        float u  = exp2f(-d2 * c2);    // exp(-L2/(16bw))
        float u2 = u * u, u4 = u2 * u2, u8 = u4 * u4, u16v = u8 * u8;
        lsum += u + u2 + u4 + u8 + u16v;
      }
    }
  }
  // sign is tile-uniform: +1 within XX/YY blocks, -1 for XY/YX
  const float sgn = ((bi < 32) == (bj < 32)) ? 1.0f : -1.0f;

  #pragma unroll
  for (int off = 32; off; off >>= 1) lsum += __shfl_down(lsum, off, 64);
  __shared__ float wsum[4];
  if (lane == 0) wsum[wave] = lsum;
  __syncthreads();
  if (tid == 0) {
    double tot = (double)wsum[0] + (double)wsum[1] + (double)wsum[2] + (double)wsum[3];
    part[blockIdx.y * gridDim.x + blockIdx.x] = tot * (double)sgn;
  }
}

// ---- K5: final reduce of 4096 block partials ----
__global__ __launch_bounds__(256) void k_final(const double* __restrict__ part,
                                               float* __restrict__ out) {
  __shared__ double red[256];
  const int t = threadIdx.x;
  double s = 0.0;
  for (int i = t; i < 4096; i += 256) s += part[i];
  red[t] = s; __syncthreads();
  for (int off = 128; off; off >>= 1) { if (t < off) red[t] += red[t + off]; __syncthreads(); }
  if (t == 0) out[0] = (float)(red[0] / ((double)NX * (double)NX));
}

extern "C" void kernel_launch(void* const* d_in, const int* in_sizes, int n_in,
                              void* d_out, int out_size, void* d_ws, size_t ws_size,
                              hipStream_t stream) {
  const float* x = (const float*)d_in[0];
  const float* y = (const float*)d_in[1];
  char* ws = (char*)d_ws;
  u16*    totbf = (u16*)(ws + OFF_TOTBF);
  float*  sq    = (float*)(ws + OFF_SQ);
  float*  colp  = (float*)(ws + OFF_COLP);
  float*  c2    = (float*)(ws + OFF_C2);
  double* part  = (double*)(ws + OFF_PART);
  float*  out   = (float*)d_out;

  hipLaunchKernelGGL(k_rows,   dim3(2048),   dim3(256), 0, stream, x, y, totbf, sq);
  hipLaunchKernelGGL(k_cols,   dim3(32),     dim3(256), 0, stream, x, y, colp);
  hipLaunchKernelGGL(k_scalar, dim3(1),      dim3(256), 0, stream, sq, colp, c2);
  hipLaunchKernelGGL(k_main,   dim3(64, 64), dim3(256), 0, stream, totbf, sq, c2, part);
  hipLaunchKernelGGL(k_final,  dim3(1),      dim3(256), 0, stream, part, out);
}

// Round 2
// 160.591 us; speedup vs baseline: 1.0526x; 1.0526x over previous
//
#include <hip/hip_runtime.h>
#include <stdint.h>

#define NTOT 8192
#define NX   4096
#define DIM  256
#define NBJ  64                      // 8192/128 tiles per dimension
#define NBLK (NBJ*(NBJ+1)/2)         // 2080 upper-triangle tiles

typedef unsigned short u16;
typedef __attribute__((ext_vector_type(8))) short  bf16x8;
typedef __attribute__((ext_vector_type(4))) float  f32x4;

// ---- workspace layout (bytes) ----
#define OFF_TOTBF   0                        // u16 [8192*256]  = 4,194,304
#define OFF_SQ      4194304                  // float[8192]     =    32,768
#define OFF_COLP    (OFF_SQ + 32768)         // float[256*256]  =   262,144
#define OFF_SQP     (OFF_COLP + 262144)      // float[256]      =     1,024
#define OFF_C2      (OFF_SQP + 1024)         // float[4]        =        16
#define OFF_PART    (OFF_C2 + 16)            // double[2080]    =    16,640
#define OFF_CNT     (OFF_PART + 16640)       // uint[4]         =        16
// total ~4.51 MB

__device__ __forceinline__ u16 f2bf(float f) {
  union { float f; unsigned int u; } v; v.f = f;
  unsigned int u = v.u;
  u += 0x7fffu + ((u >> 16) & 1u);           // round-to-nearest-even
  return (u16)(u >> 16);
}

__device__ __forceinline__ void gload16(const u16* g, u16* l) {
  // async global->LDS, 16B/lane; LDS dest = wave-uniform base + lane*16
  __builtin_amdgcn_global_load_lds(
      (const __attribute__((address_space(1))) unsigned int*)g,
      (__attribute__((address_space(3))) unsigned int*)l,
      16, 0, 0);
}

// ---- K1: fused prep. 256 blocks x 256 threads; 32 rows/block.
// Per row: fp32->bf16 convert, ||t||^2. Per block: column-sum partial,
// sq partial. Last block computes bandwidth -> c2.
__global__ __launch_bounds__(256) void k_prep(const float* __restrict__ x,
                                              const float* __restrict__ y,
                                              u16* __restrict__ totbf,
                                              float* __restrict__ sq,
                                              float* __restrict__ colpart,
                                              float* __restrict__ sqpart,
                                              float* __restrict__ c2out,
                                              unsigned int* __restrict__ cnt) {
  const int tid = threadIdx.x;
  const int wave = tid >> 6, lane = tid & 63;
  const int rbase = blockIdx.x * 32 + wave * 8;

  float4 csum = {0.f, 0.f, 0.f, 0.f};
  float ssum = 0.f;
  #pragma unroll
  for (int i = 0; i < 8; ++i) {
    const int r = rbase + i;
    const float* row = (r < NX) ? (x + (size_t)r * DIM) : (y + (size_t)(r - NX) * DIM);
    float4 v = ((const float4*)row)[lane];
    ushort4 o;
    o.x = f2bf(v.x); o.y = f2bf(v.y); o.z = f2bf(v.z); o.w = f2bf(v.w);
    ((ushort4*)(totbf + (size_t)r * DIM))[lane] = o;
    csum.x += v.x; csum.y += v.y; csum.z += v.z; csum.w += v.w;
    float s = v.x * v.x + v.y * v.y + v.z * v.z + v.w * v.w;
    #pragma unroll
    for (int off = 32; off; off >>= 1) s += __shfl_down(s, off, 64);
    if (lane == 0) { sq[r] = s; ssum += s; }
  }

  __shared__ float cpart[4 * 256];
  __shared__ float spart[4];
  ((float4*)cpart)[wave * 64 + lane] = csum;   // cols 4*lane..+3 of wave's 8 rows
  if (lane == 0) spart[wave] = ssum;
  __syncthreads();
  const float c = cpart[tid] + cpart[256 + tid] + cpart[512 + tid] + cpart[768 + tid];
  colpart[blockIdx.x * 256 + tid] = c;
  if (tid == 0) sqpart[blockIdx.x] = spart[0] + spart[1] + spart[2] + spart[3];

  // ---- last-block bandwidth computation ----
  __shared__ int lastflag;
  __syncthreads();                    // all global writes issued block-wide
  if (tid == 0) {
    __threadfence();                  // release this block's writes (device scope)
    lastflag = (atomicAdd(cnt, 1u) == 255u);
  }
  __syncthreads();
  if (!lastflag) return;
  __threadfence();                    // acquire all blocks' writes

  __shared__ double red[256];
  double v1 = (double)sqpart[tid];
  red[tid] = v1; __syncthreads();
  for (int off = 128; off; off >>= 1) { if (tid < off) red[tid] += red[tid + off]; __syncthreads(); }
  const double S1 = red[0]; __syncthreads();

  double cs = 0.0;
  #pragma unroll 8
  for (int b = 0; b < 256; ++b) cs += (double)colpart[b * 256 + tid];
  red[tid] = cs * cs; __syncthreads();
  for (int off = 128; off; off >>= 1) { if (tid < off) red[tid] += red[tid + off]; __syncthreads(); }
  if (tid == 0) {
    const double CS2 = red[0];
    const double n = (double)NTOT;
    const double S = 2.0 * n * S1 - 2.0 * CS2;    // sum(L2); clip negligible
    double bw = S / (n * n - n);
    bw *= 0.25;                                    // / KERNEL_MUL^(KERNEL_NUM//2)
    c2out[0] = (float)(1.0 / (16.0 * bw * 0.6931471805599453));
  }
}

// ---- K2: fused gram + 5-kernel RBF + signed sum, upper-triangle tiles.
// 2080 blocks x 256. BK=64, conflict-free LDS cell layout. Last block
// reduces the 2080 partials -> out.
__global__ __launch_bounds__(256) void k_main(const u16* __restrict__ totbf,
                                              const float* __restrict__ sq,
                                              const float* __restrict__ c2p,
                                              double* __restrict__ part,
                                              unsigned int* __restrict__ cnt,
                                              float* __restrict__ out) {
  __shared__ u16 sA[128 * 64];
  __shared__ u16 sB[128 * 64];
  const int tid = threadIdx.x;
  const int wave = tid >> 6, lane = tid & 63;
  const int quad = lane >> 4, l16 = lane & 15;

  // triangular decode: idx -> (bi <= bj)
  const int idx = blockIdx.x;
  int bj = (int)((sqrtf(8.0f * (float)idx + 1.0f) - 1.0f) * 0.5f);
  while ((bj + 1) * (bj + 2) / 2 <= idx) ++bj;
  while (bj * (bj + 1) / 2 > idx) --bj;
  const int bi = idx - bj * (bj + 1) / 2;

  const int wm = wave >> 1, wn = wave & 1;

  f32x4 acc[4][4];
  #pragma unroll
  for (int tm = 0; tm < 4; ++tm)
    #pragma unroll
    for (int tn = 0; tn < 4; ++tn) {
      acc[tm][tn][0] = 0.0f; acc[tm][tn][1] = 0.0f;
      acc[tm][tn][2] = 0.0f; acc[tm][tn][3] = 0.0f;
    }

  const int rowin  = lane & 7;        // row within 8-row chunk
  const int colblk = lane >> 3;       // 8-col block within 64-col slice

  for (int kk = 0; kk < DIM; kk += 64) {
    if (kk) __syncthreads();
    #pragma unroll
    for (int c = 0; c < 8; ++c) {
      const int chunk = c * 4 + wave;            // 0..31
      const int isB = chunk >> 4;
      const int ch  = chunk & 15;                // 16 chunks of 8 rows per tile
      const int grow = (isB ? bj : bi) * 128 + ch * 8 + rowin;
      const u16* g = totbf + (size_t)grow * DIM + kk + colblk * 8;
      // cell (colblk,row) at u16 offset colblk*64 + rowin*8 == lane*8
      gload16(g, (isB ? sB : sA) + ch * 512);
    }
    __syncthreads();

    #pragma unroll
    for (int s = 0; s < 2; ++s) {
      bf16x8 af[4], bfr[4];
      #pragma unroll
      for (int tm = 0; tm < 4; ++tm) {
        const int r = wm * 64 + tm * 16 + l16;
        af[tm] = *(const bf16x8*)&sA[(r >> 3) * 512 + (s * 4 + quad) * 64 + (r & 7) * 8];
      }
      #pragma unroll
      for (int tn = 0; tn < 4; ++tn) {
        const int r = wn * 64 + tn * 16 + l16;
        bfr[tn] = *(const bf16x8*)&sB[(r >> 3) * 512 + (s * 4 + quad) * 64 + (r & 7) * 8];
      }
      #pragma unroll
      for (int tm = 0; tm < 4; ++tm)
        #pragma unroll
        for (int tn = 0; tn < 4; ++tn)
          acc[tm][tn] = __builtin_amdgcn_mfma_f32_16x16x32_bf16(af[tm], bfr[tn], acc[tm][tn], 0, 0, 0);
    }
  }

  // ---- epilogue: L2 -> u + u^2 + u^4 + u^8 + u^16 ----
  const float c2 = c2p[0];
  const int gi0 = bi * 128 + wm * 64;
  const int gj0 = bj * 128 + wn * 64;
  float lsum = 0.0f;
  #pragma unroll
  for (int tn = 0; tn < 4; ++tn) {
    const float sqj = sq[gj0 + tn * 16 + l16];
    #pragma unroll
    for (int tm = 0; tm < 4; ++tm) {
      const f32x4 sqi = *(const f32x4*)&sq[gi0 + tm * 16 + quad * 4];
      const f32x4 a = acc[tm][tn];
      #pragma unroll
      for (int r = 0; r < 4; ++r) {
        float d2 = sqi[r] + sqj - 2.0f * a[r];
        d2 = fmaxf(d2, 0.0f);
        float u  = __builtin_amdgcn_exp2f(-d2 * c2);   // exp(-L2/(16bw))
        float u2 = u * u, u4 = u2 * u2, u8 = u4 * u4, u16v = u8 * u8;
        lsum += u + u2 + u4 + u8 + u16v;
      }
    }
  }
  float w = ((bi < 32) == (bj < 32)) ? 1.0f : -1.0f;   // XX/YY vs XY/YX
  if (bi != bj) w *= 2.0f;                             // symmetry weight

  #pragma unroll
  for (int off = 32; off; off >>= 1) lsum += __shfl_down(lsum, off, 64);
  __shared__ float wsum[4];
  __shared__ int lastflag;
  if (lane == 0) wsum[wave] = lsum;
  __syncthreads();
  if (tid == 0) {
    double tot = (double)wsum[0] + (double)wsum[1] + (double)wsum[2] + (double)wsum[3];
    part[idx] = tot * (double)w;
    __threadfence();                  // release part[idx]
    lastflag = (atomicAdd(cnt, 1u) == (unsigned)(NBLK - 1));
  }
  __syncthreads();
  if (!lastflag) return;
  __threadfence();                    // acquire all parts

  __shared__ double red[256];
  double s = 0.0;
  for (int i = tid; i < NBLK; i += 256) s += part[i];
  red[tid] = s; __syncthreads();
  for (int off = 128; off; off >>= 1) { if (tid < off) red[tid] += red[tid + off]; __syncthreads(); }
  if (tid == 0) out[0] = (float)(red[0] / ((double)NX * (double)NX));
}

extern "C" void kernel_launch(void* const* d_in, const int* in_sizes, int n_in,
                              void* d_out, int out_size, void* d_ws, size_t ws_size,
                              hipStream_t stream) {
  const float* x = (const float*)d_in[0];
  const float* y = (const float*)d_in[1];
  char* ws = (char*)d_ws;
  u16*    totbf = (u16*)(ws + OFF_TOTBF);
  float*  sq    = (float*)(ws + OFF_SQ);
  float*  colp  = (float*)(ws + OFF_COLP);
  float*  sqp   = (float*)(ws + OFF_SQP);
  float*  c2    = (float*)(ws + OFF_C2);
  double* part  = (double*)(ws + OFF_PART);
  unsigned int* cnt = (unsigned int*)(ws + OFF_CNT);
  float*  out   = (float*)d_out;

  hipMemsetAsync(cnt, 0, 16, stream);   // zero both atomic counters (ws is poisoned)
  hipLaunchKernelGGL(k_prep, dim3(256),  dim3(256), 0, stream, x, y, totbf, sq, colp, sqp, c2, cnt);
  hipLaunchKernelGGL(k_main, dim3(NBLK), dim3(256), 0, stream, totbf, sq, c2, part, cnt + 1, out);
}